// Round 6
// baseline (85.380 us; speedup 1.0000x reference)
//
#include <hip/hip_runtime.h>
#include <hip/hip_bf16.h>

typedef __attribute__((ext_vector_type(4))) float f32x4;
typedef __attribute__((ext_vector_type(8))) __bf16 bf16x8;

#define AS1 __attribute__((address_space(1)))
#define AS3 __attribute__((address_space(3)))

#define DDIM 512
#define BK 64

// ---------------- Kernel 1: normalize rows + positive-pair dot + rowsum zero ----
__global__ __launch_bounds__(256) void norm_pd_kernel(
    const float* __restrict__ ei, const float* __restrict__ ej,
    __hip_bfloat16* __restrict__ z, float* __restrict__ pd,
    float* __restrict__ rowsum, int N) {
  const int k = blockIdx.x;
  const int t = threadIdx.x;
  const float2 a = *reinterpret_cast<const float2*>(ei + (size_t)k * DDIM + t * 2);
  const float2 b = *reinterpret_cast<const float2*>(ej + (size_t)k * DDIM + t * 2);
  float sii = a.x * a.x + a.y * a.y;
  float sjj = b.x * b.x + b.y * b.y;
  float sij = a.x * b.x + a.y * b.y;
#pragma unroll
  for (int off = 32; off; off >>= 1) {
    sii += __shfl_down(sii, off);
    sjj += __shfl_down(sjj, off);
    sij += __shfl_down(sij, off);
  }
  __shared__ float red[3][4];
  if ((t & 63) == 0) { red[0][t >> 6] = sii; red[1][t >> 6] = sjj; red[2][t >> 6] = sij; }
  __syncthreads();
  sii = red[0][0] + red[0][1] + red[0][2] + red[0][3];
  sjj = red[1][0] + red[1][1] + red[1][2] + red[1][3];
  sij = red[2][0] + red[2][1] + red[2][2] + red[2][3];
  const float rsi = rsqrtf(sii), rsj = rsqrtf(sjj);
  __hip_bfloat162 zi, zj;
  zi.x = __float2bfloat16(a.x * rsi); zi.y = __float2bfloat16(a.y * rsi);
  zj.x = __float2bfloat16(b.x * rsj); zj.y = __float2bfloat16(b.y * rsj);
  *reinterpret_cast<__hip_bfloat162*>(z + (size_t)k * DDIM + t * 2) = zi;
  *reinterpret_cast<__hip_bfloat162*>(z + (size_t)(N + k) * DDIM + t * 2) = zj;
  if (t == 0) { pd[k] = sij * rsi * rsj; rowsum[k] = 0.0f; rowsum[N + k] = 0.0f; }
}

// ---------------- Kernel 2: 256x256-tile 8-wave fused sim-GEMM -----------------
// m201-style phase rhythm: per phase {ds_reads; (stage); BARRIER; lgkmcnt;
// MFMA cluster (setprio); BARRIER}. The mid-phase barrier lets each wave's
// ds_reads complete during barrier-crossing while other waves' MFMAs fill the
// matrix pipe (T5 role-split). Counted vmcnt(8) once per K-tile, never 0 in
// the main loop. Bank-conflict-free via XOR swizzle applied on the per-lane
// GLOBAL source of global_load_lds (LDS dest linear; rule #21).
//
// Swizzle: half-tile = 128 rows x 64 cols bf16, 16B chunks c=0..7 per row;
// stored chunk index = r*8 + (c ^ (r&7)).

#define BAR() do { __builtin_amdgcn_sched_barrier(0); __builtin_amdgcn_s_barrier(); \
                   __builtin_amdgcn_sched_barrier(0); } while (0)
#define VM_WAIT8() asm volatile("s_waitcnt vmcnt(8)" ::: "memory")
#define VM_WAIT0() asm volatile("s_waitcnt vmcnt(0)" ::: "memory")

#define READ_A(MH)                                                            \
  do {                                                                        \
    _Pragma("unroll") for (int mf = 0; mf < 4; ++mf)                          \
    _Pragma("unroll") for (int kk = 0; kk < 2; ++kk) {                        \
      const int rl = (MH) * 64 + mf * 16 + (l & 15);                          \
      Af[mf][kk] = *reinterpret_cast<const bf16x8*>(                          \
          abase + rl * 128 + ((((kk * 4) + (l >> 4)) ^ (l & 7)) << 4));       \
    }                                                                         \
  } while (0)

#define READ_B(DST, NH)                                                       \
  do {                                                                        \
    _Pragma("unroll") for (int nf = 0; nf < 2; ++nf)                          \
    _Pragma("unroll") for (int kk = 0; kk < 2; ++kk) {                        \
      const int crl = (wn & 1) * 64 + (NH) * 32 + nf * 16 + (l & 15);         \
      DST[nf][kk] = *reinterpret_cast<const bf16x8*>(                         \
          bbase + crl * 128 + ((((kk * 4) + (l >> 4)) ^ (l & 7)) << 4));      \
    }                                                                         \
  } while (0)

#define MMA(BREG, MH, NH)                                                     \
  do {                                                                        \
    __builtin_amdgcn_s_setprio(1);                                            \
    _Pragma("unroll") for (int mf = 0; mf < 4; ++mf)                          \
    _Pragma("unroll") for (int nf = 0; nf < 2; ++nf)                          \
    _Pragma("unroll") for (int kk = 0; kk < 2; ++kk)                          \
      acc[(MH) * 4 + mf][(NH) * 2 + nf] =                                     \
          __builtin_amdgcn_mfma_f32_16x16x32_bf16(                            \
              Af[mf][kk], BREG[nf][kk], acc[(MH) * 4 + mf][(NH) * 2 + nf],    \
              0, 0, 0);                                                       \
    __builtin_amdgcn_s_setprio(0);                                            \
  } while (0)

__global__ __launch_bounds__(512, 2) void simloss_main(
    const __hip_bfloat16* __restrict__ z, float* __restrict__ rowsum, int nwg) {
  // ---- bijective XCD-chunk remap (nwg = 528 = 8*66) ----
  const int orig = blockIdx.x;
  const int q = nwg >> 3, r8 = nwg & 7;
  const int xcd = orig & 7, pos = orig >> 3;
  const int t0 = (xcd < r8 ? xcd * (q + 1) : r8 * (q + 1) + (xcd - r8) * q) + pos;

  // ---- triangular decode: t0 -> (bx, by), bx <= by ----
  const float ff = sqrtf(8.0f * (float)t0 + 1.0f);
  int by = (int)((ff - 1.0f) * 0.5f);
  while ((by + 1) * (by + 2) / 2 <= t0) ++by;
  while (by * (by + 1) / 2 > t0) --by;
  const int bx = t0 - by * (by + 1) / 2;

  const int row0 = bx * 256;
  const int col0 = by * 256;

  __shared__ __hip_bfloat16 lds[2][4][128 * 64];  // [buf][Alo,Ahi,Blo,Bhi][16KB]

  const int tid = threadIdx.x;
  const int w = tid >> 6;    // wave 0..7
  const int l = tid & 63;
  const int wm = w >> 2;     // 0..1  (row half of tile)
  const int wn = w & 3;      // 0..3  (64-col strip)

  f32x4 acc[8][4] = {};

  // stage one 128x64 half-tile into lds[p][half]; global source pre-swizzled
  auto stage_half = [&](int p, int half, int baserow, int k0) {
#pragma unroll
    for (int qq = 0; qq < 2; ++qq) {
      const int rr = w * 16 + qq * 8 + (l >> 3);
      const int cc = (l & 7) ^ ((l >> 3) & 7);
      const __hip_bfloat16* g = z + (size_t)(baserow + rr) * DDIM + k0 + cc * 8;
      char* dst = (char*)&lds[p][half][0] + (unsigned)(w * 2 + qq) * 1024;  // wave-uniform
      __builtin_amdgcn_global_load_lds((const AS1 void*)g, (AS3 void*)dst, 16, 0, 0);
    }
  };

  // ---- prologue: tile0 -> buf0, tile1 -> buf1 ----
  stage_half(0, 0, row0, 0);        stage_half(0, 1, row0 + 128, 0);
  stage_half(0, 2, col0, 0);        stage_half(0, 3, col0 + 128, 0);
  stage_half(1, 0, row0, BK);       stage_half(1, 1, row0 + 128, BK);
  stage_half(1, 2, col0, BK);       stage_half(1, 3, col0 + 128, BK);
  VM_WAIT8();   // tile0's 8 loads landed
  BAR();

  bf16x8 Af[4][2], B0r[2][2], B1r[2][2];

  // ---- K-loop: 8 tiles of BK=64, 4 phases each, 2 barriers per phase ----
  for (int t = 0; t < 8; ++t) {
    const int p = t & 1;
    const int k2 = (t + 2) * BK;
    const char* abase = (const char*)&lds[p][wm][0];
    const char* bbase = (const char*)&lds[p][2 + (wn >> 1)][0];

    // ph0: (mh0, nh0)
    READ_A(0);
    READ_B(B0r, 0);
    BAR();                 // reads in flight across barrier; lgkm wait lands after
    MMA(B0r, 0, 0);
    BAR();
    // ph1: (mh0, nh1)
    READ_B(B1r, 1);
    BAR();
    MMA(B1r, 0, 1);
    BAR();
    // ph2: (mh1, nh1) — B slots fully read (pre-ph1-mid) -> stage B(t+2)
    if (t < 6) { stage_half(p, 2, col0, k2); stage_half(p, 3, col0 + 128, k2); }
    READ_A(1);
    BAR();
    MMA(B1r, 1, 1);
    BAR();
    // ph3: (mh1, nh0) — A slots fully read (pre-ph2-mid) -> stage A(t+2)
    if (t < 6) { stage_half(p, 0, row0, k2); stage_half(p, 1, row0 + 128, k2); }
    BAR();
    MMA(B0r, 1, 0);
    if (t < 6) { VM_WAIT8(); }        // tile t+1's loads all landed
    else if (t == 6) { VM_WAIT0(); }  // drain tile 7's loads
    BAR();
  }

  // ---- epilogue ----
  // frag (fi, cj): rows row0 + wm*128 + fi*16 + lgrp*4 + rg, col col0 + wn*64 + cj*16 + lcol
  const float C2L2E = 2.0f * 1.44269504088896340736f;  // 2 * log2(e)
  const int lgrp = l >> 4;
  const int lcol = l & 15;

#pragma unroll
  for (int fi = 0; fi < 8; ++fi)
#pragma unroll
    for (int cj = 0; cj < 4; ++cj)
#pragma unroll
      for (int rg = 0; rg < 4; ++rg)
        acc[fi][cj][rg] = exp2f(acc[fi][cj][rg] * C2L2E);

  // row sums over the wave's 64 cols
#pragma unroll
  for (int fi = 0; fi < 8; ++fi) {
    float rs[4];
#pragma unroll
    for (int rg = 0; rg < 4; ++rg) {
      float s = 0.0f;
#pragma unroll
      for (int cj = 0; cj < 4; ++cj) s += acc[fi][cj][rg];
      rs[rg] = s;
    }
#pragma unroll
    for (int off = 1; off < 16; off <<= 1) {
#pragma unroll
      for (int rg = 0; rg < 4; ++rg) rs[rg] += __shfl_xor(rs[rg], off);
    }
    if (lcol == 0) {
      const int rowb = row0 + wm * 128 + fi * 16 + lgrp * 4;
#pragma unroll
      for (int rg = 0; rg < 4; ++rg) atomicAdd(&rowsum[rowb + rg], rs[rg]);
    }
  }

  // column sums (mirror) — off-diagonal tiles only
  if (bx != by) {
#pragma unroll
    for (int cj = 0; cj < 4; ++cj) {
      float cs = 0.0f;
#pragma unroll
      for (int fi = 0; fi < 8; ++fi)
#pragma unroll
        for (int rg = 0; rg < 4; ++rg) cs += acc[fi][cj][rg];
      cs += __shfl_xor(cs, 16);
      cs += __shfl_xor(cs, 32);
      if (lgrp == 0) atomicAdd(&rowsum[col0 + wn * 64 + cj * 16 + lcol], cs);
    }
  }
}

// ---------------- Kernel 3: finalize (parallel, atomic partials) ----------------
__global__ __launch_bounds__(1024) void finalize_kernel(
    const float* __restrict__ rowsum, const float* __restrict__ pd,
    float* __restrict__ out, int M, int N) {
  const int i = blockIdx.x * 1024 + threadIdx.x;
  const float E2 = 7.38905609893065f;  // exp(2) — diagonal term (unit rows)
  float acc = 0.0f;
  if (i < M) {
    const float denom = rowsum[i] - E2;
    const int kk = (i < N) ? i : (i - N);
    acc = logf(denom) - 2.0f * pd[kk];
  }
#pragma unroll
  for (int off = 32; off; off >>= 1) acc += __shfl_down(acc, off);
  __shared__ float red[16];
  const int t = threadIdx.x;
  if ((t & 63) == 0) red[t >> 6] = acc;
  __syncthreads();
  if (t < 64) {
    float s = (t < 16) ? red[t] : 0.0f;
#pragma unroll
    for (int off = 8; off; off >>= 1) s += __shfl_down(s, off);
    if (t == 0) atomicAdd(out, s / (float)M);
  }
}

extern "C" void kernel_launch(void* const* d_in, const int* in_sizes, int n_in,
                              void* d_out, int out_size, void* d_ws, size_t ws_size,
                              hipStream_t stream) {
  const float* ei = (const float*)d_in[0];
  const float* ej = (const float*)d_in[1];
  float* out = (float*)d_out;

  const int N = in_sizes[0] / DDIM;  // 4096
  const int M = 2 * N;               // 8192
  const int NT = M / 256;            // 32 tiles per dim
  const int NTRI = NT * (NT + 1) / 2;  // 528 blocks

  char* ws = (char*)d_ws;
  __hip_bfloat16* z = (__hip_bfloat16*)ws;                       // M * 512 bf16
  float* pd = (float*)(ws + (size_t)M * DDIM * 2);               // N f32
  float* rowsum = (float*)(ws + (size_t)M * DDIM * 2 + (size_t)N * 4);  // M f32

  hipMemsetAsync(out, 0, sizeof(float), stream);
  norm_pd_kernel<<<N, 256, 0, stream>>>(ei, ej, z, pd, rowsum, N);
  simloss_main<<<NTRI, 512, 0, stream>>>(z, rowsum, NTRI);
  finalize_kernel<<<(M + 1023) / 1024, 1024, 0, stream>>>(rowsum, pd, out, M, N);
}

// Round 7
// 72.052 us; speedup vs baseline: 1.1850x; 1.1850x over previous
//
#include <hip/hip_runtime.h>
#include <hip/hip_bf16.h>
#include <hip/hip_fp8.h>

typedef __attribute__((ext_vector_type(4))) float f32x4;
typedef __attribute__((ext_vector_type(2))) unsigned long ulongx2;

#define AS1 __attribute__((address_space(1)))
#define AS3 __attribute__((address_space(3)))

#define DDIM 512
#define BK 64

// k-permutation within each 64-element k-block (so that one 16B chunk holds
// both kk-subfragments of one lane-group g):
//   r = k%64; g=(r&31)>>3; kk=r>>5; h=r&7; pos = g*16 + kk*8 + h
// z is stored fp8-e4m3, row-major, k-permuted ("z_perm").

// ---------------- Kernel 1: normalize + pos-pair dot + fp8 permuted write ----
__global__ __launch_bounds__(256) void norm_pd_kernel(
    const float* __restrict__ ei, const float* __restrict__ ej,
    unsigned char* __restrict__ zq, float* __restrict__ pd,
    float* __restrict__ rowsum, int N) {
  const int k = blockIdx.x;
  const int t = threadIdx.x;
  const float2 a = *reinterpret_cast<const float2*>(ei + (size_t)k * DDIM + t * 2);
  const float2 b = *reinterpret_cast<const float2*>(ej + (size_t)k * DDIM + t * 2);
  float sii = a.x * a.x + a.y * a.y;
  float sjj = b.x * b.x + b.y * b.y;
  float sij = a.x * b.x + a.y * b.y;
#pragma unroll
  for (int off = 32; off; off >>= 1) {
    sii += __shfl_down(sii, off);
    sjj += __shfl_down(sjj, off);
    sij += __shfl_down(sij, off);
  }
  __shared__ float red[3][4];
  if ((t & 63) == 0) { red[0][t >> 6] = sii; red[1][t >> 6] = sjj; red[2][t >> 6] = sij; }
  __syncthreads();
  sii = red[0][0] + red[0][1] + red[0][2] + red[0][3];
  sjj = red[1][0] + red[1][1] + red[1][2] + red[1][3];
  sij = red[2][0] + red[2][1] + red[2][2] + red[2][3];
  const float rsi = rsqrtf(sii), rsj = rsqrtf(sjj);

  // permuted byte position for elements k0, k0+1 (same 8-run, adjacent)
  const int k0 = t * 2;
  const int kb = k0 >> 6, r = k0 & 63;
  const int g = (r & 31) >> 3, kk = r >> 5, h = r & 7;
  const int pos = (kb << 6) + g * 16 + kk * 8 + h;

  __hip_fp8_e4m3 qa0(a.x * rsi), qa1(a.y * rsi);
  __hip_fp8_e4m3 qb0(b.x * rsj), qb1(b.y * rsj);
  const unsigned short wa = (unsigned short)qa0.__x | ((unsigned short)qa1.__x << 8);
  const unsigned short wb = (unsigned short)qb0.__x | ((unsigned short)qb1.__x << 8);
  *reinterpret_cast<unsigned short*>(zq + (size_t)k * DDIM + pos) = wa;
  *reinterpret_cast<unsigned short*>(zq + (size_t)(N + k) * DDIM + pos) = wb;
  if (t == 0) { pd[k] = sij * rsi * rsj; rowsum[k] = 0.0f; rowsum[N + k] = 0.0f; }
}

// ---------------- Kernel 2: 256x256-tile 8-wave fp8 fused sim-GEMM -------------
// True double-buffer, 1 phase per K-tile: {12 ds_read_b128; stage(t+1)->buf^1;
// BAR; lgkmcnt(0); 64 MFMA (setprio); vmcnt(0); BAR}. LDS 64 KiB total.
// LDS half-tile = 64 super-rows (2 rows) x 128 B; involution spos = pos^(sr&7)
// applied on the pre-permuted global source (staging) and on ds_read addrs.

#define MFMA8(A, B, C) __builtin_amdgcn_mfma_f32_16x16x32_fp8_fp8((long)(A), (long)(B), (C), 0, 0, 0)

__global__ __launch_bounds__(512, 2) void simloss_main(
    const unsigned char* __restrict__ zq, float* __restrict__ rowsum, int nwg) {
  // ---- bijective XCD-chunk remap (nwg = 528 = 8*66) ----
  const int orig = blockIdx.x;
  const int q = nwg >> 3, r8 = nwg & 7;
  const int xcd = orig & 7, pos0 = orig >> 3;
  const int t0 = (xcd < r8 ? xcd * (q + 1) : r8 * (q + 1) + (xcd - r8) * q) + pos0;

  // ---- triangular decode: t0 -> (bx, by), bx <= by ----
  const float ff = sqrtf(8.0f * (float)t0 + 1.0f);
  int by = (int)((ff - 1.0f) * 0.5f);
  while ((by + 1) * (by + 2) / 2 <= t0) ++by;
  while (by * (by + 1) / 2 > t0) --by;
  const int bx = t0 - by * (by + 1) / 2;

  const int row0 = bx * 256;
  const int col0 = by * 256;

  __shared__ unsigned char lds[2][4][8192];  // [buf][Alo,Ahi,Blo,Bhi][8KB]

  const int tid = threadIdx.x;
  const int w = tid >> 6;    // wave 0..7
  const int l = tid & 63;
  const int wm = w >> 2;     // 0..1  (row half)
  const int wn = w & 3;      // 0..3  (64-col strip)
  const int g = l >> 4;      // lane k-group

  f32x4 acc[8][4] = {};

  // stage one full K-tile (4 half-tiles) into buffer p
  auto stage_tile = [&](int p, int t) {
    const int k0 = t * BK;
    const int chunk = w * 64 + l;          // 0..511 (16B chunks of an 8KB half)
    const int sr = chunk >> 3;             // super-row 0..63
    const int spos = chunk & 7;
    const int pp = spos ^ (sr & 7);        // original position
    const int row = sr * 2 + (pp >> 2);    // row within half 0..127
    const int csrc = pp & 3;               // source 16B chunk of the k-tile
    const size_t coloff = (size_t)(k0 + csrc * 16);
#pragma unroll
    for (int half = 0; half < 4; ++half) {
      const int baserow = (half < 2 ? row0 : col0) + (half & 1) * 128;
      const unsigned char* gsrc = zq + (size_t)(baserow + row) * DDIM + coloff;
      char* dst = (char*)&lds[p][half][0] + (unsigned)(w * 1024);  // wave-uniform; lane writes +l*16
      __builtin_amdgcn_global_load_lds((const AS1 void*)gsrc, (AS3 void*)dst, 16, 0, 0);
    }
  };

  // swizzled frag address: row lr (0..127) within a half, lane-group g
#define FRAG_ADDR(base, lr) \
  ((base) + (((lr) >> 1) * 128) + (((((lr)&1) << 2 | g) ^ (((lr) >> 1) & 7)) << 4))

  // ---- prologue ----
  stage_tile(0, 0);
  asm volatile("s_waitcnt vmcnt(0)" ::: "memory");
  __builtin_amdgcn_s_barrier();

  // ---- K-loop: 8 tiles of BK=64 ----
  for (int t = 0; t < 8; ++t) {
    const int p = t & 1;
    const unsigned char* ab = &lds[p][wm][0];
    const unsigned char* bb = &lds[p][2 + (wn >> 1)][0];

    ulongx2 Af[8], Br[4];
#pragma unroll
    for (int mf = 0; mf < 8; ++mf) {
      const int lr = mf * 16 + (l & 15);
      Af[mf] = *reinterpret_cast<const ulongx2*>(FRAG_ADDR(ab, lr));
    }
#pragma unroll
    for (int nf = 0; nf < 4; ++nf) {
      const int cr = (wn & 1) * 64 + nf * 16 + (l & 15);
      Br[nf] = *reinterpret_cast<const ulongx2*>(FRAG_ADDR(bb, cr));
    }
    if (t < 7) stage_tile(p ^ 1, t + 1);
    __builtin_amdgcn_sched_barrier(0);
    __builtin_amdgcn_s_barrier();
    asm volatile("s_waitcnt lgkmcnt(0)" ::: "memory");
    __builtin_amdgcn_sched_barrier(0);
    __builtin_amdgcn_s_setprio(1);
#pragma unroll
    for (int mf = 0; mf < 8; ++mf)
#pragma unroll
      for (int nf = 0; nf < 4; ++nf) {
        acc[mf][nf] = MFMA8(Af[mf].x, Br[nf].x, acc[mf][nf]);
        acc[mf][nf] = MFMA8(Af[mf].y, Br[nf].y, acc[mf][nf]);
      }
    __builtin_amdgcn_s_setprio(0);
    __builtin_amdgcn_sched_barrier(0);
    if (t < 7) { asm volatile("s_waitcnt vmcnt(0)" ::: "memory"); }
    __builtin_amdgcn_s_barrier();
    __builtin_amdgcn_sched_barrier(0);
  }

  // ---- epilogue ----
  // frag (mf, nf): rows row0 + wm*128 + mf*16 + lgrp*4 + rg,
  //               col  col0 + wn*64  + nf*16 + lcol
  const float C2L2E = 2.0f * 1.44269504088896340736f;  // 2 * log2(e)
  const int lgrp = l >> 4;
  const int lcol = l & 15;

#pragma unroll
  for (int mf = 0; mf < 8; ++mf)
#pragma unroll
    for (int nf = 0; nf < 4; ++nf)
#pragma unroll
      for (int rg = 0; rg < 4; ++rg)
        acc[mf][nf][rg] = exp2f(acc[mf][nf][rg] * C2L2E);

  // row sums over the wave's 64 cols
#pragma unroll
  for (int mf = 0; mf < 8; ++mf) {
    float rs[4];
#pragma unroll
    for (int rg = 0; rg < 4; ++rg) {
      float s = 0.0f;
#pragma unroll
      for (int nf = 0; nf < 4; ++nf) s += acc[mf][nf][rg];
      rs[rg] = s;
    }
#pragma unroll
    for (int off = 1; off < 16; off <<= 1) {
#pragma unroll
      for (int rg = 0; rg < 4; ++rg) rs[rg] += __shfl_xor(rs[rg], off);
    }
    if (lcol == 0) {
      const int rowb = row0 + wm * 128 + mf * 16 + lgrp * 4;
#pragma unroll
      for (int rg = 0; rg < 4; ++rg) atomicAdd(&rowsum[rowb + rg], rs[rg]);
    }
  }

  // column sums (mirror) — off-diagonal tiles only
  if (bx != by) {
#pragma unroll
    for (int nf = 0; nf < 4; ++nf) {
      float cs = 0.0f;
#pragma unroll
      for (int mf = 0; mf < 8; ++mf)
#pragma unroll
        for (int rg = 0; rg < 4; ++rg) cs += acc[mf][nf][rg];
      cs += __shfl_xor(cs, 16);
      cs += __shfl_xor(cs, 32);
      if (lgrp == 0) atomicAdd(&rowsum[col0 + wn * 64 + nf * 16 + lcol], cs);
    }
  }
}

// ---------------- Kernel 3: finalize (parallel, atomic partials) ----------------
__global__ __launch_bounds__(1024) void finalize_kernel(
    const float* __restrict__ rowsum, const float* __restrict__ pd,
    float* __restrict__ out, int M, int N) {
  const int i = blockIdx.x * 1024 + threadIdx.x;
  const float E2 = 7.38905609893065f;  // exp(2) — diagonal term (unit rows)
  float acc = 0.0f;
  if (i < M) {
    const float denom = rowsum[i] - E2;
    const int kk = (i < N) ? i : (i - N);
    acc = logf(denom) - 2.0f * pd[kk];
  }
#pragma unroll
  for (int off = 32; off; off >>= 1) acc += __shfl_down(acc, off);
  __shared__ float red[16];
  const int t = threadIdx.x;
  if ((t & 63) == 0) red[t >> 6] = acc;
  __syncthreads();
  if (t < 64) {
    float s = (t < 16) ? red[t] : 0.0f;
#pragma unroll
    for (int off = 8; off; off >>= 1) s += __shfl_down(s, off);
    if (t == 0) atomicAdd(out, s / (float)M);
  }
}

extern "C" void kernel_launch(void* const* d_in, const int* in_sizes, int n_in,
                              void* d_out, int out_size, void* d_ws, size_t ws_size,
                              hipStream_t stream) {
  const float* ei = (const float*)d_in[0];
  const float* ej = (const float*)d_in[1];
  float* out = (float*)d_out;

  const int N = in_sizes[0] / DDIM;  // 4096
  const int M = 2 * N;               // 8192
  const int NT = M / 256;            // 32 tiles per dim
  const int NTRI = NT * (NT + 1) / 2;  // 528 blocks

  char* ws = (char*)d_ws;
  unsigned char* zq = (unsigned char*)ws;                        // M * 512 fp8
  float* pd = (float*)(ws + (size_t)M * DDIM);                   // N f32
  float* rowsum = (float*)(ws + (size_t)M * DDIM + (size_t)N * 4);  // M f32

  hipMemsetAsync(out, 0, sizeof(float), stream);
  norm_pd_kernel<<<N, 256, 0, stream>>>(ei, ej, zq, pd, rowsum, N);
  simloss_main<<<NTRI, 512, 0, stream>>>(zq, rowsum, NTRI);
  finalize_kernel<<<(M + 1023) / 1024, 1024, 0, stream>>>(rowsum, pd, out, M, N);
}